// Round 2
// baseline (21257.854 us; speedup 1.0000x reference)
//
#include <hip/hip_runtime.h>
#include <cstdint>

// Problem constants (from reference): B=256, C=256, H=W=15, S=8 steps.
constexpr int B_ = 256, C_ = 256, H_ = 15, W_ = 15, P_ = 225, S_ = 8;
constexpr int CHW = C_ * P_;                 // 57600
constexpr size_t NX = (size_t)B_ * CHW;      // 14,745,600

// ---------------- threefry2x32 (matches jax._src.prng lowering) -------------
// Verified by hand against Random123 KAT: tf2x32(0,0,0,0) = (6b200159,99ba4efe)
__host__ __device__ inline void tf2x32(uint32_t k0, uint32_t k1,
                                       uint32_t x0, uint32_t x1,
                                       uint32_t& o0, uint32_t& o1) {
  uint32_t ks[3] = {k0, k1, k0 ^ k1 ^ 0x1BD11BDAu};
  const uint32_t rot0[4] = {13u, 15u, 26u, 6u};
  const uint32_t rot1[4] = {17u, 29u, 16u, 24u};
  x0 += ks[0]; x1 += ks[1];
#pragma unroll
  for (int r = 0; r < 5; ++r) {
    const uint32_t* rr = (r & 1) ? rot1 : rot0;
#pragma unroll
    for (int j = 0; j < 4; ++j) {
      x0 += x1;
      x1 = (x1 << rr[j]) | (x1 >> (32 - rr[j]));
      x1 ^= x0;
    }
    x0 += ks[(r + 1) % 3];
    x1 += ks[(r + 2) % 3] + (uint32_t)(r + 1);
  }
  o0 = x0; o1 = x1;
}

__device__ inline float tf_uniform(uint32_t bits) {
  // jax.random.uniform: (bits>>9 | 0x3F800000) viewed as float, minus 1.0
  return __uint_as_float((bits >> 9) | 0x3F800000u) - 1.0f;
}

__device__ inline float elu1(float v) { return v > 0.f ? v : expm1f(v); }

// ---------------- multi-scale direct conv (fp32) ----------------------------
template <int KS, int DIL, int OFF>
__global__ void __launch_bounds__(256) conv_ms(const float* __restrict__ x,
                                               const float* __restrict__ w,
                                               const float* __restrict__ bias,
                                               float* __restrict__ out) {
  constexpr int OT = 8;
  constexpr int WP = W_ + 2 * OFF;
  constexpr int HP = H_ + 2 * OFF;
  constexpr int PP = WP * HP;
  __shared__ float xs[PP];
  const int b = blockIdx.x;
  const int o0 = blockIdx.y * OT;
  const int t = threadIdx.x;
  for (int i = t; i < PP; i += 256) xs[i] = 0.f;  // zero border once
  const int hh = t / W_, ww = t % W_;
  const bool act = t < P_;
  float acc[OT];
#pragma unroll
  for (int o = 0; o < OT; ++o) acc[o] = 0.f;
  const float* xb = x + (size_t)b * CHW;
  for (int c = 0; c < C_; ++c) {
    __syncthreads();
    if (act) xs[(hh + OFF) * WP + (ww + OFF)] = xb[c * P_ + t];
    __syncthreads();
    if (act) {
#pragma unroll
      for (int kh = 0; kh < KS; ++kh) {
#pragma unroll
        for (int kw = 0; kw < KS; ++kw) {
          float xv = xs[(hh + kh * DIL) * WP + (ww + kw * DIL)];
#pragma unroll
          for (int o = 0; o < OT; ++o) {
            acc[o] = fmaf(xv,
                          w[(((size_t)(o0 + o) * C_ + c) * KS + kh) * KS + kw],
                          acc[o]);
          }
        }
      }
    }
  }
  if (act) {
#pragma unroll
    for (int o = 0; o < OT; ++o) {
      float v = acc[o] + bias[o0 + o];
      out[((size_t)b * C_ + (o0 + o)) * P_ + t] = elu1(v);
    }
  }
}

// ---------------- 1x1 conv as per-batch GEMM (K=256) ------------------------
__global__ void __launch_bounds__(256) gemm225(const float* __restrict__ in,
                                               const float* __restrict__ w,
                                               int wld,
                                               const float* __restrict__ bias,
                                               const float* __restrict__ accin,
                                               float* __restrict__ out,
                                               int apply_elu) {
  constexpr int OT = 16, KB = 32, K = 256;
  __shared__ float xs[KB * P_];
  const int b = blockIdx.x;
  const int o0 = blockIdx.y * OT;
  const int t = threadIdx.x;
  float acc[OT];
#pragma unroll
  for (int o = 0; o < OT; ++o) acc[o] = 0.f;
  const float* inb = in + (size_t)b * K * P_;
  for (int k0 = 0; k0 < K; k0 += KB) {
    __syncthreads();
    for (int i = t; i < KB * P_; i += 256) {
      int kk = i / P_;
      int pp = i - kk * P_;
      xs[i] = inb[(size_t)(k0 + kk) * P_ + pp];
    }
    __syncthreads();
    if (t < P_) {
      for (int kk = 0; kk < KB; ++kk) {
        float xv = xs[kk * P_ + t];
#pragma unroll
        for (int o = 0; o < OT; ++o)
          acc[o] = fmaf(xv, w[(size_t)(o0 + o) * wld + (k0 + kk)], acc[o]);
      }
    }
  }
  if (t < P_) {
#pragma unroll
    for (int o = 0; o < OT; ++o) {
      float v = acc[o];
      size_t oi = ((size_t)b * C_ + (o0 + o)) * P_ + t;
      if (accin) v += accin[oi];
      if (bias) v += bias[o0 + o];
      if (apply_elu) v = elu1(v);
      out[oi] = v;
    }
  }
}

// ---------------- reductions ------------------------------------------------
__device__ inline void block_reduce_2(float& s, float& s2, float* red) {
#pragma unroll
  for (int off = 32; off > 0; off >>= 1) {
    s += __shfl_down(s, off, 64);
    s2 += __shfl_down(s2, off, 64);
  }
  int lane = threadIdx.x & 63, wv = threadIdx.x >> 6;
  if (lane == 0) { red[wv] = s; red[4 + wv] = s2; }
  __syncthreads();
  if (threadIdx.x == 0) {
    s = red[0] + red[1] + red[2] + red[3];
    s2 = red[4] + red[5] + red[6] + red[7];
  }
}

__global__ void __launch_bounds__(256) ln_stats(const float* __restrict__ y,
                                                float* __restrict__ stats) {
  __shared__ float red[8];
  const float* yb = y + (size_t)blockIdx.x * CHW;
  float s = 0.f, s2 = 0.f;
  for (int i = threadIdx.x; i < CHW; i += 256) {
    float v = yb[i];
    s += v;
    s2 = fmaf(v, v, s2);
  }
  block_reduce_2(s, s2, red);
  if (threadIdx.x == 0) {
    float m = s * (1.0f / 57600.0f);
    float var = fmaf(-m, m, s2 * (1.0f / 57600.0f));  // biased (jnp.var)
    stats[blockIdx.x] = m;
    stats[C_ + blockIdx.x] = rsqrtf(var + 1e-5f);
  }
}

__global__ void __launch_bounds__(256) ln_apply(float* __restrict__ y,
                                                const float* __restrict__ stats,
                                                const float* __restrict__ lnw,
                                                const float* __restrict__ lnb) {
  int bb = blockIdx.y;
  int r = blockIdx.x * 256 + threadIdx.x;  // 225*256 == 57600 exactly
  float m = stats[bb], rs = stats[C_ + bb];
  size_t i = (size_t)bb * CHW + r;
  float v = (y[i] - m) * rs * lnw[r] + lnb[r];
  y[i] = elu1(v);
}

__global__ void __launch_bounds__(256) var_red(const float* __restrict__ dx,
                                               float* __restrict__ vout, int s) {
  __shared__ float red[8];
  const float* db = dx + (size_t)blockIdx.x * CHW;
  float sm = 0.f, s2 = 0.f;
  for (int i = threadIdx.x; i < CHW; i += 256) {
    float v = db[i];
    sm += v;
    s2 = fmaf(v, v, s2);
  }
  block_reduce_2(sm, s2, red);
  if (threadIdx.x == 0) {
    float m = sm * (1.0f / 57600.0f);
    float v = (s2 - 57600.0f * m * m) * (1.0f / 57599.0f);  // ddof=1
    vout[blockIdx.x * S_ + s] = v;
  }
}

// ---------------- scan update with threefry noise ---------------------------
// jax_threefry_partitionable=True (default since JAX 0.4.36) path:
// per element j, (b1,b2) = threefry2x32(key, j>>32, j&0xffffffff); for 32-bit
// output the bits are b1 ^ b2. Our size < 2^32 so counter = (0, j).
__global__ void __launch_bounds__(256) step_update(
    const float* __restrict__ xc, const float* __restrict__ dx,
    float* __restrict__ xout, const float* __restrict__ sp_a,
    const float* __restrict__ ss_a, const float* __restrict__ rw_a,
    const float* __restrict__ prob_a, int s, uint32_t k0, uint32_t k1) {
  size_t t = (size_t)blockIdx.x * 256 + threadIdx.x;
  if (t >= NX) return;
  float sp = sp_a[s];
  float pss = prob_a[s] * ss_a[s];
  float rw1 = 1.0f + rw_a[s];
  uint32_t y0, y1;
  tf2x32(k0, k1, 0u, (uint32_t)t, y0, y1);
  float n = tf_uniform(y0 ^ y1);
  xout[t] = fmaf(xc[t], rw1, fmaf(dx[t], sp, n * pss));
}

// ---------------- launch ----------------------------------------------------
extern "C" void kernel_launch(void* const* d_in, const int* in_sizes, int n_in,
                              void* d_out, int out_size, void* d_ws,
                              size_t ws_size, hipStream_t stream) {
  const float* x = (const float*)d_in[0];
  const float* prob = (const float*)d_in[1];
  const float* w3 = (const float*)d_in[2];
  const float* b3 = (const float*)d_in[3];
  const float* w3d = (const float*)d_in[4];
  const float* b3d = (const float*)d_in[5];
  const float* w5 = (const float*)d_in[6];
  const float* b5 = (const float*)d_in[7];
  const float* w7 = (const float*)d_in[8];
  const float* b7 = (const float*)d_in[9];
  const float* wf = (const float*)d_in[10];
  const float* bfus = (const float*)d_in[11];
  const float* w1 = (const float*)d_in[12];
  const float* b1 = (const float*)d_in[13];
  const float* lnw = (const float*)d_in[14];
  const float* lnb = (const float*)d_in[15];
  const float* sp = (const float*)d_in[16];
  const float* ss = (const float*)d_in[17];
  const float* rw = (const float*)d_in[18];
  float* out = (float*)d_out;
  float* vout = out + NX;

  // Workspace layout (needs 2*NX*4 + 2KB ≈ 118 MB):
  float* bufA = (float*)d_ws;   // conv branch output / y / dx
  float* bufB = bufA + NX;      // fusion accumulator, then xc (in-place)
  float* stats = bufB + NX;     // mu[256], rstd[256]

  dim3 gconv(B_, C_ / 8);
  dim3 ggemm(B_, C_ / 16);

  // Multi-scale perception; fusion 1x1 decomposed into 4 accumulating GEMMs:
  // xf = elu(bf + sum_g wf[:, g*C:(g+1)*C] @ dx_g)
  conv_ms<3, 1, 1><<<gconv, 256, 0, stream>>>(x, w3, b3, bufA);
  gemm225<<<ggemm, 256, 0, stream>>>(bufA, wf + 0, 1024, nullptr, nullptr, bufB, 0);
  conv_ms<3, 2, 2><<<gconv, 256, 0, stream>>>(x, w3d, b3d, bufA);
  gemm225<<<ggemm, 256, 0, stream>>>(bufA, wf + 256, 1024, nullptr, bufB, bufB, 0);
  conv_ms<5, 1, 2><<<gconv, 256, 0, stream>>>(x, w5, b5, bufA);
  gemm225<<<ggemm, 256, 0, stream>>>(bufA, wf + 512, 1024, nullptr, bufB, bufB, 0);
  conv_ms<7, 1, 3><<<gconv, 256, 0, stream>>>(x, w7, b7, bufA);
  gemm225<<<ggemm, 256, 0, stream>>>(bufA, wf + 768, 1024, bfus, bufB, bufB, 1);
  // bufB now holds xc = xf.

  for (int si = 0; si < S_; ++si) {
    uint32_t k0s, k1s;
    tf2x32(0u, 42u, 0u, (uint32_t)si, k0s, k1s);  // fold_in(key(42), si), host-side
    // y = conv1x1(xc) + b1
    gemm225<<<ggemm, 256, 0, stream>>>(bufB, w1, 256, b1, nullptr, bufA, 0);
    // LayerNorm over (C,H,W) + ELU, in place -> dx
    ln_stats<<<B_, 256, 0, stream>>>(bufA, stats);
    ln_apply<<<dim3(P_, B_), 256, 0, stream>>>(bufA, stats, lnw, lnb);
    // unbiased var of dx per batch -> nca_var[b, si]
    var_red<<<B_, 256, 0, stream>>>(bufA, vout, si);
    // x_new = xc*(1+rw) + dx*sp + noise*prob*ss  (last step writes d_out)
    step_update<<<(int)(NX / 256), 256, 0, stream>>>(
        bufB, bufA, (si == S_ - 1) ? out : bufB, sp, ss, rw, prob, si, k0s, k1s);
  }
}

// Round 3
// 4764.593 us; speedup vs baseline: 4.4616x; 4.4616x over previous
//
#include <hip/hip_runtime.h>
#include <cstdint>

// B=256, C=256, H=W=15, S=8.
constexpr int B_ = 256, C_ = 256, H_ = 15, W_ = 15, P_ = 225, S_ = 8;
constexpr int CHW = C_ * P_;                 // 57600
constexpr size_t NX = (size_t)B_ * CHW;      // 14,745,600

typedef __attribute__((ext_vector_type(8))) short short8v;   // 8 bf16
typedef __attribute__((ext_vector_type(4))) float float4v;   // 4 fp32 acc

// ---------------- threefry2x32 (verified round 2) ---------------------------
__host__ __device__ inline void tf2x32(uint32_t k0, uint32_t k1,
                                       uint32_t x0, uint32_t x1,
                                       uint32_t& o0, uint32_t& o1) {
  uint32_t ks[3] = {k0, k1, k0 ^ k1 ^ 0x1BD11BDAu};
  const uint32_t rot0[4] = {13u, 15u, 26u, 6u};
  const uint32_t rot1[4] = {17u, 29u, 16u, 24u};
  x0 += ks[0]; x1 += ks[1];
#pragma unroll
  for (int r = 0; r < 5; ++r) {
    const uint32_t* rr = (r & 1) ? rot1 : rot0;
#pragma unroll
    for (int j = 0; j < 4; ++j) {
      x0 += x1;
      x1 = (x1 << rr[j]) | (x1 >> (32 - rr[j]));
      x1 ^= x0;
    }
    x0 += ks[(r + 1) % 3];
    x1 += ks[(r + 2) % 3] + (uint32_t)(r + 1);
  }
  o0 = x0; o1 = x1;
}

__device__ inline float tf_uniform(uint32_t bits) {
  return __uint_as_float((bits >> 9) | 0x3F800000u) - 1.0f;
}

__device__ inline float elu1(float v) { return v > 0.f ? v : expm1f(v); }

__device__ inline unsigned short f2bf(float f) {  // RNE float->bf16
  uint32_t u = __float_as_uint(f);
  return (unsigned short)((u + 0x7FFFu + ((u >> 16) & 1u)) >> 16);
}
__device__ inline float bf2f(unsigned short h) {
  return __uint_as_float(((uint32_t)h) << 16);
}

// ---------------- MFMA implicit-GEMM conv -----------------------------------
// Block=(batch, o-tile64). M=pixels(256 rows,225 valid), N=64, K=(c,delta).
// LDS: zero-padded x plane [pixel_padded][32c], stride 40 bf16 (bank-friendly).
// wt layout: [delta][o][c] bf16 (precomputed).
template <int KS, int DIL, int OFF>
__global__ void __launch_bounds__(256) conv_mfma(const float* __restrict__ x,
                                                 const unsigned short* __restrict__ wt,
                                                 const float* __restrict__ bias,
                                                 unsigned short* __restrict__ dxg) {
  constexpr int WP = W_ + 2 * OFF, HP = H_ + 2 * OFF, PP = WP * HP, LDW = 40;
  __shared__ unsigned short xs[PP * LDW];
  const int b = blockIdx.x, o0 = blockIdx.y * 64;
  const int t = threadIdx.x, wv = t >> 6, ln = t & 63, l16 = ln & 15, q = ln >> 4;
  for (int i = t; i < PP * LDW; i += 256) xs[i] = 0;  // zero borders once
  int rbase[4];
#pragma unroll
  for (int mt = 0; mt < 4; ++mt) {
    int m = wv * 64 + mt * 16 + l16;
    int mc = m < P_ ? m : P_ - 1;
    int mh = mc / 15, mw = mc - 15 * mh;
    rbase[mt] = mh * WP + mw;
  }
  float4v zero = {0.f, 0.f, 0.f, 0.f};
  float4v acc[4][4];
#pragma unroll
  for (int mt = 0; mt < 4; ++mt)
#pragma unroll
    for (int nt = 0; nt < 4; ++nt) acc[mt][nt] = zero;
  const float* xb = x + (size_t)b * CHW;
  for (int cb = 0; cb < 8; ++cb) {
    __syncthreads();
    for (int i = t; i < 32 * P_; i += 256) {
      int cl = i / P_, p = i - P_ * cl;
      int h = p / 15, w = p - 15 * h;
      xs[((h + OFF) * WP + (w + OFF)) * LDW + cl] = f2bf(xb[(cb * 32 + cl) * P_ + p]);
    }
    __syncthreads();
    const unsigned short* wtc = wt + (size_t)o0 * 256 + cb * 32;
    for (int d = 0; d < KS * KS; ++d) {
      int kh = d / KS, kw = d - KS * kh;
      int doff = (kh * WP + kw) * DIL;
      short8v bfr[4];
#pragma unroll
      for (int nt = 0; nt < 4; ++nt)
        bfr[nt] = *(const short8v*)(wtc + (size_t)d * 65536 + (nt * 16 + l16) * 256 + q * 8);
#pragma unroll
      for (int mt = 0; mt < 4; ++mt) {
        short8v af = *(const short8v*)&xs[(rbase[mt] + doff) * LDW + q * 8];
#pragma unroll
        for (int nt = 0; nt < 4; ++nt)
          acc[mt][nt] = __builtin_amdgcn_mfma_f32_16x16x32_bf16(af, bfr[nt], acc[mt][nt], 0, 0, 0);
      }
    }
  }
#pragma unroll
  for (int nt = 0; nt < 4; ++nt) {
    float bv = bias[o0 + nt * 16 + l16];
#pragma unroll
    for (int mt = 0; mt < 4; ++mt) {
#pragma unroll
      for (int r = 0; r < 4; ++r) {
        int m = wv * 64 + mt * 16 + q * 4 + r;
        if (m < P_) {
          float v = elu1(acc[mt][nt][r] + bv);
          dxg[((size_t)(b * P_ + m)) * 256 + o0 + nt * 16 + l16] = f2bf(v);
        }
      }
    }
  }
}

// ---------------- [B][P][C] GEMM: fusion (modes 0-2) and scan 1x1 (mode 3) --
__global__ void __launch_bounds__(256) gemm_bpc(
    const unsigned short* __restrict__ A, const unsigned short* __restrict__ Bw,
    int ldb, int kob, const float* __restrict__ bias, float* __restrict__ xc,
    unsigned short* __restrict__ xcbf, unsigned short* __restrict__ ybf,
    float* __restrict__ stats, int mode) {
  const int b = blockIdx.x, o0 = blockIdx.y * 64;
  const int t = threadIdx.x, wv = t >> 6, ln = t & 63, l16 = ln & 15, q = ln >> 4;
  float4v zero = {0.f, 0.f, 0.f, 0.f};
  float4v acc[4][4];
#pragma unroll
  for (int mt = 0; mt < 4; ++mt)
#pragma unroll
    for (int nt = 0; nt < 4; ++nt) acc[mt][nt] = zero;
  const unsigned short* Ab = A + (size_t)b * P_ * 256;
  int mrow[4];
#pragma unroll
  for (int mt = 0; mt < 4; ++mt) {
    int m = wv * 64 + mt * 16 + l16;
    mrow[mt] = m < P_ ? m : P_ - 1;
  }
  for (int ks = 0; ks < 8; ++ks) {
    short8v bfr[4], af[4];
#pragma unroll
    for (int nt = 0; nt < 4; ++nt)
      bfr[nt] = *(const short8v*)(Bw + (size_t)(o0 + nt * 16 + l16) * ldb + kob + ks * 32 + q * 8);
#pragma unroll
    for (int mt = 0; mt < 4; ++mt)
      af[mt] = *(const short8v*)(Ab + (size_t)mrow[mt] * 256 + ks * 32 + q * 8);
#pragma unroll
    for (int mt = 0; mt < 4; ++mt)
#pragma unroll
      for (int nt = 0; nt < 4; ++nt)
        acc[mt][nt] = __builtin_amdgcn_mfma_f32_16x16x32_bf16(af[mt], bfr[nt], acc[mt][nt], 0, 0, 0);
  }
  float s1 = 0.f, s2 = 0.f;
#pragma unroll
  for (int nt = 0; nt < 4; ++nt) {
    float bv = bias ? bias[o0 + nt * 16 + l16] : 0.f;
#pragma unroll
    for (int mt = 0; mt < 4; ++mt) {
#pragma unroll
      for (int r = 0; r < 4; ++r) {
        int m = wv * 64 + mt * 16 + q * 4 + r;
        if (m >= P_) continue;
        size_t idx = ((size_t)(b * P_ + m)) * 256 + o0 + nt * 16 + l16;
        float v = acc[mt][nt][r];
        if (mode == 0) {
          xc[idx] = v;
        } else if (mode == 1) {
          xc[idx] += v;
        } else if (mode == 2) {
          float e = elu1(xc[idx] + v + bv);
          xc[idx] = e;
          xcbf[idx] = f2bf(e);
        } else {
          v += bv;
          ybf[idx] = f2bf(v);
          s1 += v;
          s2 = fmaf(v, v, s2);
        }
      }
    }
  }
  if (mode == 3) {  // LN partial sums from fp32 pre-rounded values
    __shared__ float red[8];
#pragma unroll
    for (int off = 32; off; off >>= 1) {
      s1 += __shfl_down(s1, off, 64);
      s2 += __shfl_down(s2, off, 64);
    }
    if (ln == 0) { red[wv] = s1; red[4 + wv] = s2; }
    __syncthreads();
    if (t == 0) {
      atomicAdd(&stats[b], red[0] + red[1] + red[2] + red[3]);
      atomicAdd(&stats[256 + b], red[4] + red[5] + red[6] + red[7]);
    }
  }
}

__global__ void stats_fin(float* stats) {
  int b = threadIdx.x;
  float s1 = stats[b], s2 = stats[256 + b];
  float m = s1 * (1.0f / 57600.0f);
  float var = s2 * (1.0f / 57600.0f) - m * m;
  stats[512 + b] = m;
  stats[768 + b] = rsqrtf(var + 1e-5f);
  stats[b] = 0.f;
  stats[256 + b] = 0.f;  // ready for next step
}

// ---------------- fused LN-apply + ELU + var partials + threefry update -----
__global__ void __launch_bounds__(256) step_fused(
    const unsigned short* __restrict__ ybf, float* __restrict__ xc,
    unsigned short* __restrict__ xcbf, const float* __restrict__ stats,
    float* __restrict__ vpart, const float* __restrict__ lnwT,
    const float* __restrict__ lnbT, const float* __restrict__ sp_a,
    const float* __restrict__ ss_a, const float* __restrict__ rw_a,
    const float* __restrict__ prob_a, int s, uint32_t k0, uint32_t k1, int last) {
  const int p = blockIdx.x, b = blockIdx.y, c = threadIdx.x;
  const float m = stats[512 + b], rs = stats[768 + b];
  const size_t idx = ((size_t)(b * P_ + p)) * 256 + c;
  float y = bf2f(ybf[idx]);
  float dx = elu1(fmaf((y - m) * rs, lnwT[p * 256 + c], lnbT[p * 256 + c]));
  float s1 = dx, s2 = dx * dx;
  __shared__ float red[8];
#pragma unroll
  for (int off = 32; off; off >>= 1) {
    s1 += __shfl_down(s1, off, 64);
    s2 += __shfl_down(s2, off, 64);
  }
  int wv = c >> 6, ln = c & 63;
  if (ln == 0) { red[wv] = s1; red[4 + wv] = s2; }
  __syncthreads();
  if (c == 0) {
    atomicAdd(&vpart[s * 512 + b], red[0] + red[1] + red[2] + red[3]);
    atomicAdd(&vpart[s * 512 + 256 + b], red[4] + red[5] + red[6] + red[7]);
  }
  uint32_t j = (uint32_t)(b * CHW + c * P_ + p);  // [B,C,H,W] flat order
  uint32_t y0, y1;
  tf2x32(k0, k1, 0u, j, y0, y1);
  float n = tf_uniform(y0 ^ y1);
  float xn = fmaf(xc[idx], 1.0f + rw_a[s], fmaf(dx, sp_a[s], n * (prob_a[s] * ss_a[s])));
  xc[idx] = xn;
  if (!last) xcbf[idx] = f2bf(xn);
}

__global__ void var_fin(const float* __restrict__ vpart, float* __restrict__ out) {
  int i = blockIdx.x * 256 + threadIdx.x;  // 2048
  int s = i & 7, b = i >> 3;
  float s1 = vpart[s * 512 + b], s2 = vpart[s * 512 + 256 + b];
  float m = s1 * (1.0f / 57600.0f);
  float v = (s2 - 57600.0f * m * m) * (1.0f / 57599.0f);
  out[NX + (size_t)b * 8 + s] = v;
}

// ---------------- final transpose xc [B][P][C] -> out [B][C][P] -------------
__global__ void __launch_bounds__(256) final_tr(const float* __restrict__ xc,
                                                float* __restrict__ out) {
  __shared__ float ts[64][226];
  const int b = blockIdx.x, c0 = blockIdx.y * 64;
  for (int i = threadIdx.x; i < 64 * P_; i += 256) {
    int cl = i & 63, p = i >> 6;
    ts[cl][p] = xc[((size_t)(b * P_ + p)) * 256 + c0 + cl];
  }
  __syncthreads();
  for (int i = threadIdx.x; i < 64 * P_; i += 256) {
    int cl = i / P_, p = i - P_ * cl;
    out[((size_t)(b * 256 + c0 + cl)) * P_ + p] = ts[cl][p];
  }
}

// ---------------- weight / LN prep ------------------------------------------
__global__ void wt_prep(const float* __restrict__ w, unsigned short* __restrict__ wt,
                        int ks2) {
  int i = blockIdx.x * 256 + threadIdx.x;
  if (i >= 65536 * ks2) return;
  int c = i & 255, rest = i >> 8, o = rest & 255, d = rest >> 8;
  wt[((size_t)d * 256 + o) * 256 + c] = f2bf(w[((size_t)(o * 256 + c)) * ks2 + d]);
}

__global__ void cast_bf(const float* __restrict__ in, unsigned short* __restrict__ o,
                        int n) {
  int i = blockIdx.x * 256 + threadIdx.x;
  if (i < n) o[i] = f2bf(in[i]);
}

__global__ void ln_tr(const float* __restrict__ lw, const float* __restrict__ lb,
                      float* __restrict__ ow, float* __restrict__ ob) {
  int p = blockIdx.x, c = threadIdx.x;
  ow[p * 256 + c] = lw[c * P_ + p];
  ob[p * 256 + c] = lb[c * P_ + p];
}

// ---------------- launch ----------------------------------------------------
extern "C" void kernel_launch(void* const* d_in, const int* in_sizes, int n_in,
                              void* d_out, int out_size, void* d_ws,
                              size_t ws_size, hipStream_t stream) {
  const float* x = (const float*)d_in[0];
  const float* prob = (const float*)d_in[1];
  const float* w3 = (const float*)d_in[2];
  const float* b3 = (const float*)d_in[3];
  const float* w3d = (const float*)d_in[4];
  const float* b3d = (const float*)d_in[5];
  const float* w5 = (const float*)d_in[6];
  const float* b5 = (const float*)d_in[7];
  const float* w7 = (const float*)d_in[8];
  const float* b7 = (const float*)d_in[9];
  const float* wf = (const float*)d_in[10];
  const float* bfus = (const float*)d_in[11];
  const float* w1 = (const float*)d_in[12];
  const float* b1 = (const float*)d_in[13];
  const float* lnw = (const float*)d_in[14];
  const float* lnb = (const float*)d_in[15];
  const float* sp = (const float*)d_in[16];
  const float* ss = (const float*)d_in[17];
  const float* rw = (const float*)d_in[18];
  float* out = (float*)d_out;

  // ws (proven 118 MB budget): xc fp32 | xc_bf | dx_g / y_bf
  float* xc = (float*)d_ws;                                  // 58,982,400 B
  unsigned short* xcbf = (unsigned short*)((char*)d_ws + 58982400);   // 29,491,200 B
  unsigned short* dxg = (unsigned short*)((char*)d_ws + 88473600);    // 29,491,200 B

  // d_out[0..NX*4) is scratch until the final kernels.
  char* sc = (char*)d_out;
  unsigned short* wT3 = (unsigned short*)(sc + 0);
  unsigned short* wT3d = (unsigned short*)(sc + 1179648);
  unsigned short* wT5 = (unsigned short*)(sc + 2359296);
  unsigned short* wT7 = (unsigned short*)(sc + 5636096);
  unsigned short* wfT = (unsigned short*)(sc + 12058624);
  unsigned short* w1T = (unsigned short*)(sc + 12582912);
  float* lnwT = (float*)(sc + 12713984);
  float* lnbT = (float*)(sc + 12944384);
  float* stats = (float*)(sc + 13174784);  // s1|s2|mean|rstd : 1024 floats
  float* vpart = (float*)(sc + 13178880);  // [8][2][256] : 4096 floats

  hipMemsetAsync(stats, 0, 20480, stream);  // stats + vpart

  // Prep: weight transposes + casts + LN transpose
  wt_prep<<<(65536 * 9 + 255) / 256, 256, 0, stream>>>(w3, wT3, 9);
  wt_prep<<<(65536 * 9 + 255) / 256, 256, 0, stream>>>(w3d, wT3d, 9);
  wt_prep<<<(65536 * 25 + 255) / 256, 256, 0, stream>>>(w5, wT5, 25);
  wt_prep<<<(65536 * 49 + 255) / 256, 256, 0, stream>>>(w7, wT7, 49);
  cast_bf<<<1024, 256, 0, stream>>>(wf, wfT, 262144);
  cast_bf<<<256, 256, 0, stream>>>(w1, w1T, 65536);
  ln_tr<<<P_, 256, 0, stream>>>(lnw, lnb, lnwT, lnbT);

  dim3 g(B_, 4);
  // Multi-scale convs + fusion (accumulated in xc fp32)
  conv_mfma<3, 1, 1><<<g, 256, 0, stream>>>(x, wT3, b3, dxg);
  gemm_bpc<<<g, 256, 0, stream>>>(dxg, wfT, 1024, 0, nullptr, xc, nullptr, nullptr, nullptr, 0);
  conv_mfma<3, 2, 2><<<g, 256, 0, stream>>>(x, wT3d, b3d, dxg);
  gemm_bpc<<<g, 256, 0, stream>>>(dxg, wfT, 1024, 256, nullptr, xc, nullptr, nullptr, nullptr, 1);
  conv_mfma<5, 1, 2><<<g, 256, 0, stream>>>(x, wT5, b5, dxg);
  gemm_bpc<<<g, 256, 0, stream>>>(dxg, wfT, 1024, 512, nullptr, xc, nullptr, nullptr, nullptr, 1);
  conv_mfma<7, 1, 3><<<g, 256, 0, stream>>>(x, wT7, b7, dxg);
  gemm_bpc<<<g, 256, 0, stream>>>(dxg, wfT, 1024, 768, bfus, xc, xcbf, nullptr, nullptr, 2);

  unsigned short* ybf = dxg;  // reuse region
  for (int si = 0; si < S_; ++si) {
    uint32_t k0s, k1s;
    tf2x32(0u, 42u, 0u, (uint32_t)si, k0s, k1s);  // fold_in(key(42), si)
    gemm_bpc<<<g, 256, 0, stream>>>(xcbf, w1T, 256, 0, b1, nullptr, nullptr, ybf, stats, 3);
    stats_fin<<<1, 256, 0, stream>>>(stats);
    step_fused<<<dim3(P_, B_), 256, 0, stream>>>(ybf, xc, xcbf, stats, vpart, lnwT,
                                                 lnbT, sp, ss, rw, prob, si, k0s, k1s,
                                                 si == S_ - 1);
  }

  var_fin<<<8, 256, 0, stream>>>(vpart, out);       // writes out[NX..NX+2048)
  final_tr<<<dim3(B_, 4), 256, 0, stream>>>(xc, out);  // overwrites scratch region
}

// Round 5
// 2481.330 us; speedup vs baseline: 8.5671x; 1.9202x over previous
//
#include <hip/hip_runtime.h>
#include <cstdint>

// B=256, C=256, H=W=15, S=8.
constexpr int B_ = 256, C_ = 256, H_ = 15, W_ = 15, P_ = 225, S_ = 8;
constexpr int CHW = C_ * P_;                 // 57600
constexpr size_t NX = (size_t)B_ * CHW;      // 14,745,600

typedef __attribute__((ext_vector_type(4))) short short4v;
typedef __attribute__((ext_vector_type(8))) short short8v;
typedef __attribute__((ext_vector_type(16))) float float16v;

// ---------------- threefry2x32 (verified rounds 2-3) ------------------------
__host__ __device__ inline void tf2x32(uint32_t k0, uint32_t k1,
                                       uint32_t x0, uint32_t x1,
                                       uint32_t& o0, uint32_t& o1) {
  uint32_t ks[3] = {k0, k1, k0 ^ k1 ^ 0x1BD11BDAu};
  const uint32_t rot0[4] = {13u, 15u, 26u, 6u};
  const uint32_t rot1[4] = {17u, 29u, 16u, 24u};
  x0 += ks[0]; x1 += ks[1];
#pragma unroll
  for (int r = 0; r < 5; ++r) {
    const uint32_t* rr = (r & 1) ? rot1 : rot0;
#pragma unroll
    for (int j = 0; j < 4; ++j) {
      x0 += x1;
      x1 = (x1 << rr[j]) | (x1 >> (32 - rr[j]));
      x1 ^= x0;
    }
    x0 += ks[(r + 1) % 3];
    x1 += ks[(r + 2) % 3] + (uint32_t)(r + 1);
  }
  o0 = x0; o1 = x1;
}

__device__ inline float tf_uniform(uint32_t bits) {
  return __uint_as_float((bits >> 9) | 0x3F800000u) - 1.0f;
}

__device__ inline float elu1(float v) { return v > 0.f ? v : expm1f(v); }

__device__ inline unsigned short f2bf(float f) {  // RNE float->bf16
  uint32_t u = __float_as_uint(f);
  return (unsigned short)((u + 0x7FFFu + ((u >> 16) & 1u)) >> 16);
}
__device__ inline float bf2f(unsigned short h) {
  return __uint_as_float(((uint32_t)h) << 16);
}

// LDS rows: stride 36 shorts (18 dwords, gcd(18,32)=2 -> 2-way, free).
__device__ inline short8v ld8(const unsigned short* p) {
  short4v a = *(const short4v*)p;
  short4v b = *(const short4v*)(p + 4);
  return __builtin_shufflevector(a, b, 0, 1, 2, 3, 4, 5, 6, 7);
}
__device__ inline void st8(unsigned short* p, short8v v) {
  *(short4v*)p = __builtin_shufflevector(v, v, 0, 1, 2, 3);
  *(short4v*)(p + 4) = __builtin_shufflevector(v, v, 4, 5, 6, 7);
}

// ---------------- MFMA implicit-GEMM conv (32x32x16, 8 waves, N=256) --------
template <int KS, int DIL, int OFF>
__global__ void __launch_bounds__(512, 2) conv_mfma(
    const unsigned short* __restrict__ xbf, const unsigned short* __restrict__ wt,
    const float* __restrict__ bias, unsigned short* __restrict__ dxg) {
  constexpr int KS2 = KS * KS, WP = W_ + 2 * OFF, PP = WP * (H_ + 2 * OFF);
  __shared__ unsigned short lsA[PP * 36];
  __shared__ unsigned short lsB[256 * 36];
  const int b = blockIdx.x;
  const int t = threadIdx.x, wv = t >> 6, l = t & 63;
  const int m32 = l & 31, kh8 = l >> 5;
  const int mp = wv & 3, nq = wv >> 2;
  for (int i = t; i < PP * 36; i += 512) lsA[i] = 0;  // zero borders once
  int rbase[2];
#pragma unroll
  for (int mt = 0; mt < 2; ++mt) {
    int m = (mp * 2 + mt) * 32 + m32;
    int pc = m < P_ ? m : P_ - 1;
    int ph = pc / 15, pw = pc - 15 * ph;
    // Window base in padded coords is (ph, pw): ih = ph + kh*DIL - OFF, and
    // staging adds +OFF, so read index = ph*WP + pw + DIL*(kh*WP + kw).
    // (Round-4 bug: extra +OFF here walked off the end of lsA -> NaN.)
    rbase[mt] = ph * WP + pw;
  }
  float16v acc[2][4];
#pragma unroll
  for (int mt = 0; mt < 2; ++mt)
#pragma unroll
    for (int nt = 0; nt < 4; ++nt)
#pragma unroll
      for (int r = 0; r < 16; ++r) acc[mt][nt][r] = 0.f;
  const unsigned short* xb = xbf + (size_t)b * P_ * 256;
  for (int cb = 0; cb < 8; ++cb) {
    __syncthreads();
    for (int i = t; i < 900; i += 512) {
      int p = i >> 2, c8 = (i & 3) * 8;
      short8v v = *(const short8v*)(xb + p * 256 + cb * 32 + c8);
      int ph = p / 15, pw = p - 15 * ph;
      st8(&lsA[((ph + OFF) * WP + pw + OFF) * 36 + c8], v);
    }
    const unsigned short* wcb = wt + (size_t)(cb * KS2) * 8192;
    for (int d = 0; d < KS2; ++d) {
      __syncthreads();
      for (int i = t; i < 1024; i += 512) {
        int o = i >> 2, c8 = (i & 3) * 8;
        short8v v = *(const short8v*)(wcb + d * 8192 + o * 32 + c8);
        st8(&lsB[o * 36 + c8], v);
      }
      __syncthreads();
      const int kh = d / KS, kw = d - KS * kh;
      const int doff = DIL * (kh * WP + kw);
#pragma unroll
      for (int k16 = 0; k16 < 2; ++k16) {
        const int ko = k16 * 16 + kh8 * 8;
        short8v af[2], bfr[4];
#pragma unroll
        for (int mt = 0; mt < 2; ++mt)
          af[mt] = ld8(&lsA[(rbase[mt] + doff) * 36 + ko]);
#pragma unroll
        for (int nt = 0; nt < 4; ++nt)
          bfr[nt] = ld8(&lsB[((nq * 4 + nt) * 32 + m32) * 36 + ko]);
#pragma unroll
        for (int mt = 0; mt < 2; ++mt)
#pragma unroll
          for (int nt = 0; nt < 4; ++nt)
            acc[mt][nt] = __builtin_amdgcn_mfma_f32_32x32x16_bf16(
                af[mt], bfr[nt], acc[mt][nt], 0, 0, 0);
      }
    }
  }
#pragma unroll
  for (int nt = 0; nt < 4; ++nt) {
    int o = (nq * 4 + nt) * 32 + m32;
    float bv = bias[o];
#pragma unroll
    for (int mt = 0; mt < 2; ++mt) {
#pragma unroll
      for (int r = 0; r < 16; ++r) {
        int pixel = (mp * 2 + mt) * 32 + 8 * (r >> 2) + (r & 3) + 4 * kh8;
        if (pixel < P_)
          dxg[((size_t)(b * P_ + pixel)) * 256 + o] = f2bf(elu1(acc[mt][nt][r] + bv));
      }
    }
  }
}

// ---------------- K-blocked GEMM on [B][P][C] (fusion + scan 1x1) -----------
// modes: 0 = write xc; 1 = xc += v; 2 = elu(xc+v+bias) -> xc & xcbf;
//        3 = v+bias -> ybf, block-local LN sums -> stats.
__global__ void __launch_bounds__(512, 2) gemm_kc(
    const unsigned short* __restrict__ A, int rs, int nkb,
    const unsigned short* __restrict__ Bw, const float* __restrict__ bias,
    float* __restrict__ xc, unsigned short* __restrict__ xcbf,
    unsigned short* __restrict__ ybf, float* __restrict__ stats, int mode) {
  __shared__ unsigned short lsA[P_ * 36];
  __shared__ unsigned short lsB[256 * 36];
  __shared__ float red[16];
  const int b = blockIdx.x;
  const int t = threadIdx.x, wv = t >> 6, l = t & 63;
  const int m32 = l & 31, kh8 = l >> 5;
  const int mp = wv & 3, nq = wv >> 2;
  int prow[2];
#pragma unroll
  for (int mt = 0; mt < 2; ++mt) {
    int m = (mp * 2 + mt) * 32 + m32;
    prow[mt] = m < P_ ? m : P_ - 1;
  }
  float16v acc[2][4];
#pragma unroll
  for (int mt = 0; mt < 2; ++mt)
#pragma unroll
    for (int nt = 0; nt < 4; ++nt)
#pragma unroll
      for (int r = 0; r < 16; ++r) acc[mt][nt][r] = 0.f;
  const unsigned short* Ab = A + (size_t)b * P_ * rs;
  for (int kb = 0; kb < nkb; ++kb) {
    __syncthreads();
    for (int i = t; i < 900; i += 512) {
      int p = i >> 2, c8 = (i & 3) * 8;
      short8v v = *(const short8v*)(Ab + (size_t)p * rs + kb * 32 + c8);
      st8(&lsA[p * 36 + c8], v);
    }
    for (int i = t; i < 1024; i += 512) {
      int o = i >> 2, c8 = (i & 3) * 8;
      short8v v = *(const short8v*)(Bw + (size_t)kb * 8192 + o * 32 + c8);
      st8(&lsB[o * 36 + c8], v);
    }
    __syncthreads();
#pragma unroll
    for (int k16 = 0; k16 < 2; ++k16) {
      const int ko = k16 * 16 + kh8 * 8;
      short8v af[2], bfr[4];
#pragma unroll
      for (int mt = 0; mt < 2; ++mt) af[mt] = ld8(&lsA[prow[mt] * 36 + ko]);
#pragma unroll
      for (int nt = 0; nt < 4; ++nt)
        bfr[nt] = ld8(&lsB[((nq * 4 + nt) * 32 + m32) * 36 + ko]);
#pragma unroll
      for (int mt = 0; mt < 2; ++mt)
#pragma unroll
        for (int nt = 0; nt < 4; ++nt)
          acc[mt][nt] = __builtin_amdgcn_mfma_f32_32x32x16_bf16(
              af[mt], bfr[nt], acc[mt][nt], 0, 0, 0);
    }
  }
  float s1 = 0.f, s2 = 0.f;
#pragma unroll
  for (int nt = 0; nt < 4; ++nt) {
    int o = (nq * 4 + nt) * 32 + m32;
    float bv = bias ? bias[o] : 0.f;
#pragma unroll
    for (int mt = 0; mt < 2; ++mt) {
#pragma unroll
      for (int r = 0; r < 16; ++r) {
        int pixel = (mp * 2 + mt) * 32 + 8 * (r >> 2) + (r & 3) + 4 * kh8;
        if (pixel >= P_) continue;
        size_t idx = ((size_t)(b * P_ + pixel)) * 256 + o;
        float v = acc[mt][nt][r];
        if (mode == 0) {
          xc[idx] = v;
        } else if (mode == 1) {
          xc[idx] += v;
        } else if (mode == 2) {
          float e = elu1(xc[idx] + v + bv);
          xc[idx] = e;
          xcbf[idx] = f2bf(e);
        } else {
          v += bv;
          ybf[idx] = f2bf(v);
          s1 += v;
          s2 = fmaf(v, v, s2);
        }
      }
    }
  }
  if (mode == 3) {
#pragma unroll
    for (int off = 32; off; off >>= 1) {
      s1 += __shfl_down(s1, off, 64);
      s2 += __shfl_down(s2, off, 64);
    }
    if (l == 0) { red[wv] = s1; red[8 + wv] = s2; }
    __syncthreads();
    if (t == 0) {
      float a = 0.f, c2 = 0.f;
#pragma unroll
      for (int w = 0; w < 8; ++w) { a += red[w]; c2 += red[8 + w]; }
      stats[b] = a;
      stats[256 + b] = c2;
    }
  }
}

// ---------------- fused LN-apply + ELU + var + threefry update --------------
__global__ void __launch_bounds__(512) step_fused(
    const unsigned short* __restrict__ ybf, float* __restrict__ xc,
    unsigned short* __restrict__ xcbf, const float* __restrict__ stats,
    const float* __restrict__ lnwT, const float* __restrict__ lnbT,
    const float* __restrict__ sp_a, const float* __restrict__ ss_a,
    const float* __restrict__ rw_a, const float* __restrict__ prob_a,
    int s, uint32_t k0, uint32_t k1, int last, float* __restrict__ vout) {
  __shared__ float red[16];
  const int b = blockIdx.x, t = threadIdx.x;
  const float mean = stats[b] * (1.0f / 57600.0f);
  const float var = stats[256 + b] * (1.0f / 57600.0f) - mean * mean;
  const float rstd = rsqrtf(var + 1e-5f);
  const float sp = sp_a[s], pss = prob_a[s] * ss_a[s], rw1 = 1.0f + rw_a[s];
  float s1 = 0.f, s2 = 0.f;
  const size_t base = (size_t)b * CHW;
  for (int i = t; i < CHW; i += 512) {
    int p = i >> 8, c = i & 255;
    size_t idx = base + i;  // == (b*225+p)*256 + c
    float y = bf2f(ybf[idx]);
    float dx = elu1(fmaf((y - mean) * rstd, lnwT[i], lnbT[i]));
    s1 += dx;
    s2 = fmaf(dx, dx, s2);
    uint32_t j = (uint32_t)b * 57600u + (uint32_t)(c * 225 + p);  // BCHW flat
    uint32_t y0, y1;
    tf2x32(k0, k1, 0u, j, y0, y1);
    float n = tf_uniform(y0 ^ y1);
    float xn = fmaf(xc[idx], rw1, fmaf(dx, sp, n * pss));
    xc[idx] = xn;
    if (!last) xcbf[idx] = f2bf(xn);
  }
  int wv = t >> 6, l = t & 63;
#pragma unroll
  for (int off = 32; off; off >>= 1) {
    s1 += __shfl_down(s1, off, 64);
    s2 += __shfl_down(s2, off, 64);
  }
  if (l == 0) { red[wv] = s1; red[8 + wv] = s2; }
  __syncthreads();
  if (t == 0) {
    float a = 0.f, c2 = 0.f;
#pragma unroll
    for (int w = 0; w < 8; ++w) { a += red[w]; c2 += red[8 + w]; }
    float mv = a * (1.0f / 57600.0f);
    vout[b * 8 + s] = (c2 - 57600.0f * mv * mv) * (1.0f / 57599.0f);
  }
}

// ---------------- prep + epilogue kernels -----------------------------------
__global__ void __launch_bounds__(256) prep_x(const float* __restrict__ x,
                                              unsigned short* __restrict__ xbf) {
  __shared__ unsigned short ts[64 * 232];
  const int b = blockIdx.x, c0 = blockIdx.y * 64;
  const float* xs = x + ((size_t)b * 256 + c0) * P_;
  for (int i = threadIdx.x; i < 64 * P_; i += 256) {
    int c = i / P_, p = i - P_ * c;
    ts[c * 232 + p] = f2bf(xs[c * P_ + p]);
  }
  __syncthreads();
  for (int i = threadIdx.x; i < 64 * P_; i += 256) {
    int p = i >> 6, c = i & 63;
    xbf[((size_t)b * P_ + p) * 256 + c0 + c] = ts[c * 232 + p];
  }
}

__global__ void wt_prep(const float* __restrict__ w, unsigned short* __restrict__ wt,
                        int ks2) {
  int i = blockIdx.x * 256 + threadIdx.x;
  if (i >= 65536 * ks2) return;
  int cl = i & 31, o = (i >> 5) & 255, cbd = i >> 13;
  int d = cbd % ks2, cb = cbd / ks2;
  wt[i] = f2bf(w[((size_t)(o * 256) + cb * 32 + cl) * ks2 + d]);
}

__global__ void wk_prep(const float* __restrict__ w, unsigned short* __restrict__ wt,
                        int K) {
  int i = blockIdx.x * 256 + threadIdx.x;
  if (i >= K * 256) return;
  int kc = i & 31, o = (i >> 5) & 255, kb = i >> 13;
  wt[i] = f2bf(w[(size_t)o * K + kb * 32 + kc]);
}

__global__ void ln_tr(const float* __restrict__ lw, const float* __restrict__ lb,
                      float* __restrict__ ow, float* __restrict__ ob) {
  int p = blockIdx.x, c = threadIdx.x;
  ow[p * 256 + c] = lw[c * P_ + p];
  ob[p * 256 + c] = lb[c * P_ + p];
}

__global__ void __launch_bounds__(256) final_tr(const float* __restrict__ xc,
                                                float* __restrict__ out) {
  __shared__ float ts[64][226];
  const int b = blockIdx.x, c0 = blockIdx.y * 64;
  for (int i = threadIdx.x; i < 64 * P_; i += 256) {
    int cl = i & 63, p = i >> 6;
    ts[cl][p] = xc[((size_t)(b * P_ + p)) * 256 + c0 + cl];
  }
  __syncthreads();
  for (int i = threadIdx.x; i < 64 * P_; i += 256) {
    int cl = i / P_, p = i - P_ * cl;
    out[((size_t)(b * 256 + c0 + cl)) * P_ + p] = ts[cl][p];
  }
}

// ---------------- launch ----------------------------------------------------
extern "C" void kernel_launch(void* const* d_in, const int* in_sizes, int n_in,
                              void* d_out, int out_size, void* d_ws,
                              size_t ws_size, hipStream_t stream) {
  const float* x = (const float*)d_in[0];
  const float* prob = (const float*)d_in[1];
  const float* w3 = (const float*)d_in[2];
  const float* b3 = (const float*)d_in[3];
  const float* w3d = (const float*)d_in[4];
  const float* b3d = (const float*)d_in[5];
  const float* w5 = (const float*)d_in[6];
  const float* b5 = (const float*)d_in[7];
  const float* w7 = (const float*)d_in[8];
  const float* b7 = (const float*)d_in[9];
  const float* wf = (const float*)d_in[10];
  const float* bfus = (const float*)d_in[11];
  const float* w1 = (const float*)d_in[12];
  const float* b1 = (const float*)d_in[13];
  const float* lnw = (const float*)d_in[14];
  const float* lnb = (const float*)d_in[15];
  const float* sp = (const float*)d_in[16];
  const float* ss = (const float*)d_in[17];
  const float* rw = (const float*)d_in[18];
  float* out = (float*)d_out;

  // ws layout (117,964,800 B, proven budget):
  unsigned short* xbf = (unsigned short*)d_ws;                      // 29,491,200
  float* xc = (float*)((char*)d_ws + 29491200);                     // 58,982,400
  unsigned short* dxg = (unsigned short*)((char*)d_ws + 88473600);  // 29,491,200
  unsigned short* xcbf = xbf;  // reuse: xbf dead after conv7
  unsigned short* ybf = dxg;   // reuse: dxg dead after fusion

  // d_out[0..NX*4) is scratch until final_tr.
  char* sc = (char*)d_out;
  unsigned short* wT3 = (unsigned short*)(sc + 0);
  unsigned short* wT3d = (unsigned short*)(sc + 1179648);
  unsigned short* wT5 = (unsigned short*)(sc + 2359296);
  unsigned short* wT7 = (unsigned short*)(sc + 5636096);
  unsigned short* wfT = (unsigned short*)(sc + 12058624);
  unsigned short* w1T = (unsigned short*)(sc + 12582912);
  float* lnwT = (float*)(sc + 12713984);
  float* lnbT = (float*)(sc + 12944384);
  float* stats = (float*)(sc + 13174784);  // [2][256] raw sums

  prep_x<<<dim3(B_, 4), 256, 0, stream>>>(x, xbf);
  wt_prep<<<(65536 * 9 + 255) / 256, 256, 0, stream>>>(w3, wT3, 9);
  wt_prep<<<(65536 * 9 + 255) / 256, 256, 0, stream>>>(w3d, wT3d, 9);
  wt_prep<<<(65536 * 25 + 255) / 256, 256, 0, stream>>>(w5, wT5, 25);
  wt_prep<<<(65536 * 49 + 255) / 256, 256, 0, stream>>>(w7, wT7, 49);
  wk_prep<<<1024, 256, 0, stream>>>(wf, wfT, 1024);
  wk_prep<<<256, 256, 0, stream>>>(w1, w1T, 256);
  ln_tr<<<P_, 256, 0, stream>>>(lnw, lnb, lnwT, lnbT);

  conv_mfma<3, 1, 1><<<B_, 512, 0, stream>>>(xbf, wT3, b3, dxg);
  gemm_kc<<<B_, 512, 0, stream>>>(dxg, 256, 8, wfT, nullptr, xc, nullptr, nullptr, nullptr, 0);
  conv_mfma<3, 2, 2><<<B_, 512, 0, stream>>>(xbf, wT3d, b3d, dxg);
  gemm_kc<<<B_, 512, 0, stream>>>(dxg, 256, 8, wfT + 65536, nullptr, xc, nullptr, nullptr, nullptr, 1);
  conv_mfma<5, 1, 2><<<B_, 512, 0, stream>>>(xbf, wT5, b5, dxg);
  gemm_kc<<<B_, 512, 0, stream>>>(dxg, 256, 8, wfT + 131072, nullptr, xc, nullptr, nullptr, nullptr, 1);
  conv_mfma<7, 1, 3><<<B_, 512, 0, stream>>>(xbf, wT7, b7, dxg);
  gemm_kc<<<B_, 512, 0, stream>>>(dxg, 256, 8, wfT + 196608, bfus, xc, xcbf, nullptr, nullptr, 2);

  gemm_kc<<<B_, 512, 0, stream>>>(xcbf, 256, 8, w1T, b1, nullptr, nullptr, ybf, stats, 3);
  for (int si = 0; si < S_; ++si) {
    uint32_t k0s, k1s;
    tf2x32(0u, 42u, 0u, (uint32_t)si, k0s, k1s);  // fold_in(key(42), si)
    step_fused<<<B_, 512, 0, stream>>>(ybf, xc, xcbf, stats, lnwT, lnbT, sp, ss, rw,
                                       prob, si, k0s, k1s, si == S_ - 1, out + NX);
    if (si < S_ - 1)
      gemm_kc<<<B_, 512, 0, stream>>>(xcbf, 256, 8, w1T, b1, nullptr, nullptr, ybf, stats, 3);
  }

  final_tr<<<dim3(B_, 4), 256, 0, stream>>>(xc, out);
}